// Round 6
// baseline (584.632 us; speedup 1.0000x reference)
//
#include <hip/hip_runtime.h>
#include <hip/hip_bf16.h>
#include <cstdint>
#include <cstddef>

#define N_NODES 50000
#define N_EDGES 600000
#define DF 128
#define N_ETYPES 4
#define N_STEPS 5
#define N4 (N_NODES * 4)           // per-(node,etype) segment count
#define SCAN_NB4 782               // ceil(200000/256)
#define GRU_TILES 3125             // 50000/16 exact
#define GRU_BLOCKS 256             // k_gru: 1 block/CU (regs incl AGPR ~140/wave)
#define AGG_BLOCKS 512             // k_aggmm: 512-thr blocks, 2/CU if VGPR<=128
#define LSTRIDE 130                // k_gru LDS row stride (floats)
#define TSTRIDE 136                // out-tile row stride (f16)
#define SSTRIDE 520                // s-tile row stride (f16): 260 dwords % 32 = 4 -> even bank spread
#define FILL_CHUNKS 2344           // ceil(600000/256)
#define FILL_RANGE (N_NODES / 8)   // 6250 nodes per XCD range

typedef _Float16 f16x8 __attribute__((ext_vector_type(8)));
typedef _Float16 f16x4 __attribute__((ext_vector_type(4)));
typedef float f32x4 __attribute__((ext_vector_type(4)));

__device__ __forceinline__ float sigmoid_fast(float x) {
    return 1.0f / (1.0f + __expf(-x));
}
__device__ __forceinline__ float tanh_fast(float x) {
    return 1.0f - 2.0f / (__expf(2.0f * x) + 1.0f);
}

// ---------------- setup kernels (once per launch) ----------------

// Wl -> f16; build concatenated GRU B matrix Bc[g*128+c][k]: k<128 -> wih, else whh
__global__ __launch_bounds__(256) void k_cvt_w(
    const float* __restrict__ Wl, const float* __restrict__ wih,
    const float* __restrict__ whh, _Float16* __restrict__ Wl_h,
    _Float16* __restrict__ Bc) {
    int i = blockIdx.x * 256 + threadIdx.x;          // grid covers 98304
    if (i < N_ETYPES * DF * DF) Wl_h[i] = (_Float16)Wl[i];
    int row = i >> 8;                                // 0..383 = g*128 + c
    int k = i & 255;
    float v = (k < 128) ? wih[row * 128 + k] : whh[row * 128 + (k - 128)];
    Bc[i] = (_Float16)v;
}

__global__ __launch_bounds__(256) void k_cvt_h(
    const float* __restrict__ h, _Float16* __restrict__ hh, int n4) {
    int i = blockIdx.x * 256 + threadIdx.x;
    if (i < n4) {
        float4 v = ((const float4*)h)[i];
        f16x4 o;
        o.x = (_Float16)v.x; o.y = (_Float16)v.y;
        o.z = (_Float16)v.z; o.w = (_Float16)v.w;
        ((f16x4*)hh)[i] = o;
    }
}

// per-(dst, etype) degree histogram over 200K bins
__global__ __launch_bounds__(256) void k_hist4(
    const int* __restrict__ dst, const int* __restrict__ ety,
    int* __restrict__ deg4, int E) {
    int i = blockIdx.x * 256 + threadIdx.x;
    if (i < E) atomicAdd(&deg4[dst[i] * 4 + (ety[i] - 1)], 1);
}

// hierarchical exclusive scan over deg4[0..N)
__global__ __launch_bounds__(256) void k_part(
    const int* __restrict__ deg, int* __restrict__ part, int N) {
    __shared__ int s[256];
    int t = threadIdx.x, i = blockIdx.x * 256 + t;
    s[t] = (i < N) ? deg[i] : 0;
    __syncthreads();
    for (int off = 128; off > 0; off >>= 1) {
        if (t < off) s[t] += s[t + off];
        __syncthreads();
    }
    if (t == 0) part[blockIdx.x] = s[0];
}

// single-block scan of up to 1024 partials (SCAN_NB4 = 782)
__global__ __launch_bounds__(1024) void k_scan1(int* __restrict__ part, int nb) {
    __shared__ int s[1024];
    int t = threadIdx.x;
    int v = (t < nb) ? part[t] : 0;
    s[t] = v;
    __syncthreads();
    for (int off = 1; off < 1024; off <<= 1) {
        int u = (t >= off) ? s[t - off] : 0;
        __syncthreads();
        s[t] += u;
        __syncthreads();
    }
    if (t < nb) part[t] = s[t] - v;
}

__global__ __launch_bounds__(256) void k_row(
    const int* __restrict__ deg, const int* __restrict__ part,
    int* __restrict__ row_start, int* __restrict__ cursor, int N) {
    __shared__ int s[256];
    int t = threadIdx.x, i = blockIdx.x * 256 + t;
    int d = (i < N) ? deg[i] : 0;
    s[t] = d;
    __syncthreads();
    for (int off = 1; off < 256; off <<= 1) {
        int u = (t >= off) ? s[t - off] : 0;
        __syncthreads();
        s[t] += u;
        __syncthreads();
    }
    int rs = part[blockIdx.x] + s[t] - d;
    if (i < N) {
        row_start[i] = rs;
        cursor[i] = rs;
        if (i == N - 1) row_start[N] = rs + d;
    }
}

// XCD-partitioned CSR scatter (R5 win), now into per-(dst,etype) segments.
// csr entries = src only (segment position encodes dst+etype).
__global__ __launch_bounds__(256) void k_fill4(
    const int* __restrict__ src, const int* __restrict__ dst,
    const int* __restrict__ ety, int* __restrict__ cursor4,
    int* __restrict__ csr, int E) {
    const int range = blockIdx.x & 7;
    const int chunk = blockIdx.x >> 3;
    const int e = chunk * 256 + threadIdx.x;
    const int lo = range * FILL_RANGE;
    const int hi = lo + FILL_RANGE;
    if (e < E) {
        int d = dst[e];
        if (d >= lo && d < hi) {
            int slot = atomicAdd(&cursor4[d * 4 + (ety[e] - 1)], 1);
            csr[slot] = src[e];
        }
    }
}

// ---------------- per-step kernels ----------------

// FUSED aggregate+multiply (replaces k_lin + k_agg). Uses linearity:
//   a[n] = sum_et W[et] @ (sum_{type-et in-edges} h[src]) + sum_et deg_et[n]*b_lin[et]
// Gather table shrinks 51.2MB (t) -> 12.8MB (h, L2/L3-resident); t_half gone.
// 8 waves/block; wave w = output col-slice w AND aggregator of nodes 2w,2w+1.
// Phase A: per node, the 4 lane-quads aggregate the 4 etype segments
// CONCURRENTLY (per-quad f32 acc -> no runtime reg indexing), 2 edges in
// flight per quad; s-tile written to LDS f16. Phase B: K=512 MFMA with
// persistent W frags (64 VGPR, loaded once). Double-buffered S/O, ONE
// __syncthreads per tile; next tile's gathers issued before this tile's MFMA.
__global__ __launch_bounds__(512) void k_aggmm(
    const _Float16* __restrict__ hh, const int* __restrict__ rs4,
    const int* __restrict__ csr, const _Float16* __restrict__ Wl,
    const float* __restrict__ b_lin, _Float16* __restrict__ ah, int N) {
    __shared__ _Float16 S[2][16][SSTRIDE];           // s-tile: [buf][node][et*128+d]
    __shared__ float DC[2][16][4];                   // per-(node,et) degree
    __shared__ _Float16 O[2][16 * TSTRIDE];          // out-tile
    const int wave = threadIdx.x >> 6, lane = threadIdx.x & 63;
    const int col16 = lane & 15, quad = lane >> 4;

    // persistent W frags: output col f = wave*16+col16; k = et*128 + d,
    // kt 0..15: et = kt>>2, d = (kt&3)*32 + quad*8 (+j)
    f16x8 b[16];
#pragma unroll
    for (int kt = 0; kt < 16; kt++) {
        const _Float16* bp = Wl + ((size_t)(kt >> 2) * DF + wave * 16 + col16) * DF
                           + (kt & 3) * 32 + quad * 8;
        b[kt] = *(const f16x8*)bp;
    }
    float blv[4];
#pragma unroll
    for (int et = 0; et < 4; et++) blv[et] = b_lin[et * DF + wave * 16 + col16];

    auto AGG = [&](int tile, int buf) {
#pragma unroll
        for (int half = 0; half < 2; half++) {
            const int nl = wave * 2 + half;
            const int n = tile * 16 + nl;
            const int* rp = rs4 + (size_t)n * 4;
            int4 rr = *(const int4*)rp;              // starts of et 0..3
            int rend = rp[4];                        // end of et3 = next node start
            int begq = (quad == 0) ? rr.x : (quad == 1) ? rr.y : (quad == 2) ? rr.z : rr.w;
            int endq = (quad == 0) ? rr.y : (quad == 1) ? rr.z : (quad == 2) ? rr.w : rend;
            float a8[8] = {0.f, 0.f, 0.f, 0.f, 0.f, 0.f, 0.f, 0.f};
            for (int e = begq; e < endq; e += 2) {   // 2 gathers in flight per quad
                int j1 = (e + 1 < endq) ? e + 1 : e;
                float m1 = (e + 1 < endq) ? 1.f : 0.f;
                int p0 = csr[e], p1 = csr[j1];
                f16x8 x0 = *(const f16x8*)(hh + ((size_t)p0 << 7) + col16 * 8);
                f16x8 x1 = *(const f16x8*)(hh + ((size_t)p1 << 7) + col16 * 8);
#pragma unroll
                for (int j = 0; j < 8; j++) a8[j] += (float)x0[j] + m1 * (float)x1[j];
            }
            f16x8 o;
#pragma unroll
            for (int j = 0; j < 8; j++) o[j] = (_Float16)a8[j];
            *(f16x8*)&S[buf][nl][quad * 128 + col16 * 8] = o;
            if (col16 == 0) DC[buf][nl][quad] = (float)(endq - begq);
        }
    };

    int it = 0;
    AGG(blockIdx.x, 0);
    __syncthreads();
    for (int tile = blockIdx.x; tile < GRU_TILES; tile += AGG_BLOCKS, ++it) {
        const int nxt = tile + AGG_BLOCKS;
        const int buf = it & 1;
        if (nxt < GRU_TILES) AGG(nxt, buf ^ 1);      // prefetch next tile's s

        // Phase B: 16 MFMA over K=512. A-frag row = col16 (node), k as in b[].
        f32x4 acc = {0.f, 0.f, 0.f, 0.f};
#pragma unroll
        for (int kt = 0; kt < 16; kt++) {
            f16x8 a = *(const f16x8*)&S[buf][col16][(kt >> 2) * 128 + (kt & 3) * 32 + quad * 8];
            acc = __builtin_amdgcn_mfma_f32_16x16x32_f16(a, b[kt], acc, 0, 0, 0);
        }
#pragma unroll
        for (int i = 0; i < 4; i++) {
            int r = quad * 4 + i;
            float bias = DC[buf][r][0] * blv[0] + DC[buf][r][1] * blv[1]
                       + DC[buf][r][2] * blv[2] + DC[buf][r][3] * blv[3];
            O[buf][r * TSTRIDE + wave * 16 + col16] = (_Float16)(acc[i] + bias);
        }
        __syncthreads();                             // S/DC(buf^1) + O(buf) complete
        if (threadIdx.x < 256) {
            int row = threadIdx.x >> 4, c8 = threadIdx.x & 15;
            f16x8 v = *(const f16x8*)&O[buf][row * TSTRIDE + c8 * 8];
            *(f16x8*)(ah + ((size_t)(tile * 16 + row) << 7) + c8 * 8) = v;
        }
    }
}

// GRU, gate-parallel, software-pipelined (unchanged from R3 — verified win).
__global__ __launch_bounds__(768) void k_gru(
    const _Float16* __restrict__ ah, const _Float16* __restrict__ hh,
    const _Float16* __restrict__ Bc, const float* __restrict__ b_ih,
    const float* __restrict__ b_hh, _Float16* __restrict__ hh_next,
    float* __restrict__ out_f32) {
    __shared__ float X[2][4 * 16 * LSTRIDE];         // double-buffered gate exchange
    __shared__ __align__(16) char Ast[4][8192];      // A-tile ring: [slot][ah 4KB | hh 4KB]
    const int wave = threadIdx.x >> 6, lane = threadIdx.x & 63;
    const int col16 = lane & 15, quad = lane >> 4;
    const int g = wave >> 2;                         // gate 0..2
    const int s = wave & 3;                          // col-slice of 32

    // persistent B fragments: rows (g*128 + s*32 + ct*16 + col16), k = kt*32+quad*8
    f16x8 b[2][8];
#pragma unroll
    for (int ct = 0; ct < 2; ct++) {
        const _Float16* bp = Bc + (((size_t)(g * 128 + s * 32 + ct * 16 + col16)) << 8) + quad * 8;
#pragma unroll
        for (int kt = 0; kt < 8; kt++) b[ct][kt] = *(const f16x8*)(bp + kt * 32);
    }

    const int olocal = (wave & 3) * 1024 + lane * 16;   // within-part byte offset
    const int oswl = olocal ^ (((olocal >> 8) & 7) << 4);
    const char* sbase = (wave < 4) ? (const char*)ah : (const char*)hh;

    const int abase = col16 * 256 + quad * 16;
    const int axor = (col16 & 7) << 4;

    auto STAGE = [&](int iter) {
        if (wave < 8) {
            int tt = blockIdx.x + iter * GRU_BLOCKS;
            if (tt >= GRU_TILES) tt = GRU_TILES - 1;  // clamp keeps vmcnt accounting uniform
            const char* gp = sbase + (size_t)tt * 4096 + oswl;
            char* lp = &Ast[iter & 3][wave * 1024];   // wave-uniform base; HW adds lane*16
            __builtin_amdgcn_global_load_lds(
                (const __attribute__((address_space(1))) void*)gp,
                (__attribute__((address_space(3))) void*)lp, 16, 0, 0);
        }
    };

    STAGE(0);
    STAGE(1);
    asm volatile("s_waitcnt vmcnt(1)" ::: "memory");
    __builtin_amdgcn_s_barrier();
    __builtin_amdgcn_sched_barrier(0);

    int it = 0;
    for (int tile = blockIdx.x; tile < GRU_TILES; tile += GRU_BLOCKS, ++it) {
        const int r0 = tile * 16;
        STAGE(it + 2);                               // 2-deep prefetch into ring slot

        const char* As = (const char*)Ast[it & 3];
        float* Xb = X[it & 1];

        f16x8 A[8];                                  // kt<4 = ah part, kt>=4 = hh part
#pragma unroll
        for (int kt = 0; kt < 8; kt++) {
            int off = ((kt & 4) << 10) + abase + (kt & 3) * 64;
            off ^= axor;                             // undo staging swizzle
            A[kt] = *(const f16x8*)(As + off);
        }

        f32x4 acc[2][2];                             // [khalf-set][ct]; g<2 uses set 0 only
#pragma unroll
        for (int u = 0; u < 2; u++)
#pragma unroll
            for (int ct = 0; ct < 2; ct++) acc[u][ct] = (f32x4){0.f, 0.f, 0.f, 0.f};
#pragma unroll
        for (int kt = 0; kt < 8; kt++) {
            const int set = (g == 2 && kt >= 4) ? 1 : 0;
#pragma unroll
            for (int ct = 0; ct < 2; ct++)
                acc[set][ct] = __builtin_amdgcn_mfma_f32_16x16x32_f16(
                    A[kt], b[ct][kt], acc[set][ct], 0, 0, 0);
        }

        // acc -> LDS exchange (double-buffered)
#pragma unroll
        for (int ct = 0; ct < 2; ct++) {
            const int cbase = s * 32 + ct * 16 + col16;
            if (g < 2) {
#pragma unroll
                for (int i = 0; i < 4; i++)
                    Xb[g * (16 * LSTRIDE) + (quad * 4 + i) * LSTRIDE + cbase] = acc[0][ct][i];
            } else {
#pragma unroll
                for (int i = 0; i < 4; i++) {
                    Xb[2 * (16 * LSTRIDE) + (quad * 4 + i) * LSTRIDE + cbase] = acc[0][ct][i];
                    Xb[3 * (16 * LSTRIDE) + (quad * 4 + i) * LSTRIDE + cbase] = acc[1][ct][i];
                }
            }
        }

        asm volatile("s_waitcnt vmcnt(1) lgkmcnt(0)" ::: "memory");
        __builtin_amdgcn_s_barrier();
        __builtin_amdgcn_sched_barrier(0);

        // epilogue: 2048 elems over 768 threads; hprev from staged hh in LDS
#pragma unroll
        for (int pazz = 0; pazz < 3; pazz++) {
            int e = threadIdx.x + pazz * 768;
            if (e < 2048) {
                int row = e >> 7, col = e & 127;
                float vr = Xb[0 * (16 * LSTRIDE) + row * LSTRIDE + col];
                float vz = Xb[1 * (16 * LSTRIDE) + row * LSTRIDE + col];
                float vin = Xb[2 * (16 * LSTRIDE) + row * LSTRIDE + col];
                float vhn = Xb[3 * (16 * LSTRIDE) + row * LSTRIDE + col];
                float r = sigmoid_fast(vr + b_ih[col] + b_hh[col]);
                float z = sigmoid_fast(vz + b_ih[128 + col] + b_hh[128 + col]);
                float nn = tanh_fast(vin + b_ih[256 + col] + r * (vhn + b_hh[256 + col]));
                int hoff = (4096 + row * 256 + col * 2) ^ ((row & 7) << 4);
                float hprev = (float)*(const _Float16*)(As + hoff);
                float hv = (1.f - z) * nn + z * hprev;
                size_t idx = ((size_t)(r0 + row) << 7) + col;
                hh_next[idx] = (_Float16)hv;
                if (out_f32) out_f32[idx] = hv;
            }
        }
    }
    asm volatile("s_waitcnt vmcnt(0)" ::: "memory"); // drain ring prefetch before endpgm
}

// ---------------- launch ----------------

extern "C" void kernel_launch(void* const* d_in, const int* in_sizes, int n_in,
                              void* d_out, int out_size, void* d_ws, size_t ws_size,
                              hipStream_t stream) {
    const float* h0    = (const float*)d_in[0];
    const int*   src   = (const int*)d_in[1];
    const int*   dst   = (const int*)d_in[2];
    const int*   ety   = (const int*)d_in[3];
    const float* W_lin = (const float*)d_in[4];
    const float* b_lin = (const float*)d_in[5];
    const float* w_ih  = (const float*)d_in[6];
    const float* w_hh  = (const float*)d_in[7];
    const float* b_ih  = (const float*)d_in[8];
    const float* b_hh  = (const float*)d_in[9];
    float* hout = (float*)d_out;

    char* p = (char*)d_ws;
    auto alloc = [&](size_t bytes) -> char* {
        char* r = p;
        p += (bytes + 255) & ~(size_t)255;
        return r;
    };
    _Float16* h_a    = (_Float16*)alloc((size_t)N_NODES * DF * 2);
    _Float16* h_b    = (_Float16*)alloc((size_t)N_NODES * DF * 2);
    _Float16* a_half = (_Float16*)alloc((size_t)N_NODES * DF * 2);
    _Float16* Wl_h   = (_Float16*)alloc((size_t)N_ETYPES * DF * DF * 2);
    _Float16* Bc     = (_Float16*)alloc((size_t)3 * DF * 2 * DF * 2);   // [384][256] f16
    int* deg4    = (int*)alloc((size_t)N4 * 4);
    int* rs4     = (int*)alloc((size_t)(N4 + 1) * 4);
    int* cursor4 = (int*)alloc((size_t)N4 * 4);
    int* csr     = (int*)alloc((size_t)N_EDGES * 4);
    int* part    = (int*)alloc((size_t)1024 * 4);

    hipMemsetAsync(deg4, 0, (size_t)N4 * 4, stream);
    k_cvt_w<<<384, 256, 0, stream>>>(W_lin, w_ih, w_hh, Wl_h, Bc);
    k_cvt_h<<<(N_NODES * DF / 4 + 255) / 256, 256, 0, stream>>>(h0, h_a, N_NODES * DF / 4);
    k_hist4<<<FILL_CHUNKS, 256, 0, stream>>>(dst, ety, deg4, N_EDGES);
    k_part<<<SCAN_NB4, 256, 0, stream>>>(deg4, part, N4);
    k_scan1<<<1, 1024, 0, stream>>>(part, SCAN_NB4);
    k_row<<<SCAN_NB4, 256, 0, stream>>>(deg4, part, rs4, cursor4, N4);
    k_fill4<<<FILL_CHUNKS * 8, 256, 0, stream>>>(src, dst, ety, cursor4, csr, N_EDGES);

    _Float16* hc = h_a;
    _Float16* hn = h_b;
    for (int s = 0; s < N_STEPS; s++) {
        k_aggmm<<<AGG_BLOCKS, 512, 0, stream>>>(hc, rs4, csr, Wl_h, b_lin, a_half, N_NODES);
        float* of = (s == N_STEPS - 1) ? hout : nullptr;
        k_gru<<<GRU_BLOCKS, 768, 0, stream>>>(a_half, hc, Bc, b_ih, b_hh, hn, of);
        _Float16* tmp = hc; hc = hn; hn = tmp;
    }
}

// Round 7
// 522.330 us; speedup vs baseline: 1.1193x; 1.1193x over previous
//
#include <hip/hip_runtime.h>
#include <hip/hip_bf16.h>
#include <cstdint>
#include <cstddef>

#define N_NODES 50000
#define N_EDGES 600000
#define DF 128
#define N_ETYPES 4
#define N_STEPS 5
#define SCAN_NB 196        // ceil(50000/256)
#define GRU_TILES 3125     // 50000/16 exact
#define GRU_BLOCKS 256     // 1 block/CU
#define LIN_BLOCKS 256     // k_lin: 1024-thread persistent-weight blocks
#define TSTRIDE 136        // k_lin LDS out-tile row stride (f16)
#define FILL_CHUNKS 2344   // ceil(600000/256)
#define FILL_RANGE (N_NODES / 8)   // 6250 nodes per XCD range

typedef _Float16 f16x8 __attribute__((ext_vector_type(8)));
typedef _Float16 f16x4 __attribute__((ext_vector_type(4)));
typedef float f32x4 __attribute__((ext_vector_type(4)));

__device__ __forceinline__ float sigmoid_fast(float x) {
    return 1.0f / (1.0f + __expf(-x));
}
__device__ __forceinline__ float tanh_fast(float x) {
    return 1.0f - 2.0f / (__expf(2.0f * x) + 1.0f);
}

// ---------------- setup kernels (once per launch) ----------------

// merged: Wl->f16 + Bc build + h->f16 + degree histogram (independent work,
// one launch instead of three). grid = 6250 covers the largest range (1.6M).
__global__ __launch_bounds__(256) void k_setup(
    const float* __restrict__ Wl, const float* __restrict__ wih,
    const float* __restrict__ whh, const float* __restrict__ h,
    const int* __restrict__ dst,
    _Float16* __restrict__ Wl_h, _Float16* __restrict__ Bc,
    _Float16* __restrict__ hh, int* __restrict__ deg) {
    int i = blockIdx.x * 256 + threadIdx.x;
    if (i < N_ETYPES * DF * DF * 3 / 2) {            // 98304: Bc (+ Wl_h for i<65536)
        if (i < N_ETYPES * DF * DF) Wl_h[i] = (_Float16)Wl[i];
        int row = i >> 8;                            // 0..383 = g*128 + c
        int k = i & 255;
        float v = (k < 128) ? wih[row * 128 + k] : whh[row * 128 + (k - 128)];
        Bc[i] = (_Float16)v;
    }
    if (i < N_NODES * DF / 4) {                      // 1.6M float4 chunks
        float4 v = ((const float4*)h)[i];
        f16x4 o;
        o.x = (_Float16)v.x; o.y = (_Float16)v.y;
        o.z = (_Float16)v.z; o.w = (_Float16)v.w;
        ((f16x4*)hh)[i] = o;
    }
    if (i < N_EDGES) atomicAdd(&deg[dst[i]], 1);
}

// hierarchical exclusive scan over deg[0..N)
__global__ __launch_bounds__(256) void k_part(
    const int* __restrict__ deg, int* __restrict__ part, int N) {
    __shared__ int s[256];
    int t = threadIdx.x, i = blockIdx.x * 256 + t;
    s[t] = (i < N) ? deg[i] : 0;
    __syncthreads();
    for (int off = 128; off > 0; off >>= 1) {
        if (t < off) s[t] += s[t + off];
        __syncthreads();
    }
    if (t == 0) part[blockIdx.x] = s[0];
}

__global__ __launch_bounds__(256) void k_scan1(int* __restrict__ part, int nb) {
    __shared__ int s[256];
    int t = threadIdx.x;
    int v = (t < nb) ? part[t] : 0;
    s[t] = v;
    __syncthreads();
    for (int off = 1; off < 256; off <<= 1) {
        int u = (t >= off) ? s[t - off] : 0;
        __syncthreads();
        s[t] += u;
        __syncthreads();
    }
    if (t < nb) part[t] = s[t] - v;
}

__global__ __launch_bounds__(256) void k_row(
    const int* __restrict__ deg, const int* __restrict__ part,
    int* __restrict__ row_start, int* __restrict__ cursor, int N) {
    __shared__ int s[256];
    int t = threadIdx.x, i = blockIdx.x * 256 + t;
    int d = (i < N) ? deg[i] : 0;
    s[t] = d;
    __syncthreads();
    for (int off = 1; off < 256; off <<= 1) {
        int u = (t >= off) ? s[t - off] : 0;
        __syncthreads();
        s[t] += u;
        __syncthreads();
    }
    int rs = part[blockIdx.x] + s[t] - d;
    if (i < N) {
        row_start[i] = rs;
        cursor[i] = rs;
        if (i == N - 1) row_start[N] = rs + d;
    }
}

// XCD-partitioned CSR scatter (R5 verified win: WRITE_SIZE 36.7MB -> ~4MB).
__global__ __launch_bounds__(256) void k_fill(
    const int* __restrict__ src, const int* __restrict__ dst,
    const int* __restrict__ ety, int* __restrict__ cursor,
    int* __restrict__ csr, int E) {
    const int range = blockIdx.x & 7;
    const int chunk = blockIdx.x >> 3;
    const int e = chunk * 256 + threadIdx.x;
    const int lo = range * FILL_RANGE;
    const int hi = lo + FILL_RANGE;
    if (e < E) {
        int d = dst[e];
        if (d >= lo && d < hi) {
            int slot = atomicAdd(&cursor[d], 1);
            csr[slot] = src[e] | ((ety[e] - 1) << 16);   // src < 65536, et in 0..3
        }
    }
}

// ---------------- per-step kernels ----------------

// t[k][n][f] = sum_d h[n,d] * W[k][f,d] + b_lin[k][f]  (R4 verified win)
__global__ __launch_bounds__(1024) void k_lin(
    const _Float16* __restrict__ hh, const _Float16* __restrict__ Wl,
    const float* __restrict__ b_lin, _Float16* __restrict__ t_out, int N) {
    __shared__ _Float16 O[2][N_ETYPES * 16 * TSTRIDE];   // double-buffered out-tile
    __shared__ __align__(16) char Ast[4][4096];          // h-tile ring (16 rows x 256B)
    const int wave = threadIdx.x >> 6, lane = threadIdx.x & 63;
    const int col16 = lane & 15, quad = lane >> 4;
    const int g = wave >> 2;                         // etype 0..3
    const int s = wave & 3;                          // col-slice of 32

    f16x8 b[2][4];
#pragma unroll
    for (int ct = 0; ct < 2; ct++) {
        const _Float16* bp = Wl + (size_t)g * DF * DF
                           + (size_t)(s * 32 + ct * 16 + col16) * DF + quad * 8;
#pragma unroll
        for (int kt = 0; kt < 4; kt++) b[ct][kt] = *(const f16x8*)(bp + kt * 32);
    }
    const float bias0 = b_lin[g * DF + s * 32 + col16];
    const float bias1 = b_lin[g * DF + s * 32 + 16 + col16];

    const int olocal = (wave & 3) * 1024 + lane * 16;
    const int oswl = olocal ^ (((olocal >> 8) & 7) << 4);
    const int abase = col16 * 256 + quad * 16;
    const int axor = (col16 & 7) << 4;

    auto STAGE = [&](int iter) {
        if (wave < 4) {
            int tt = blockIdx.x + iter * LIN_BLOCKS;
            if (tt >= GRU_TILES) tt = GRU_TILES - 1;
            const char* gp = (const char*)hh + (size_t)tt * 4096 + oswl;
            char* lp = &Ast[iter & 3][(wave & 3) * 1024];
            __builtin_amdgcn_global_load_lds(
                (const __attribute__((address_space(1))) void*)gp,
                (__attribute__((address_space(3))) void*)lp, 16, 0, 0);
        }
    };

    const int ek = threadIdx.x >> 8;
    const int erow = (threadIdx.x & 255) >> 4;
    const int ec8 = threadIdx.x & 15;

    STAGE(0);
    STAGE(1);
    asm volatile("s_waitcnt vmcnt(1)" ::: "memory");
    __builtin_amdgcn_s_barrier();
    __builtin_amdgcn_sched_barrier(0);

    int it = 0;
    for (int tile = blockIdx.x; tile < GRU_TILES; tile += LIN_BLOCKS, ++it) {
        const int r0 = tile * 16;
        STAGE(it + 2);

        const char* As = (const char*)Ast[it & 3];
        _Float16* Ob = O[it & 1];

        f16x8 A[4];
#pragma unroll
        for (int kt = 0; kt < 4; kt++) {
            int off = (abase + kt * 64) ^ axor;
            A[kt] = *(const f16x8*)(As + off);
        }

        f32x4 acc0 = {0.f, 0.f, 0.f, 0.f}, acc1 = {0.f, 0.f, 0.f, 0.f};
#pragma unroll
        for (int kt = 0; kt < 4; kt++) {
            acc0 = __builtin_amdgcn_mfma_f32_16x16x32_f16(A[kt], b[0][kt], acc0, 0, 0, 0);
            acc1 = __builtin_amdgcn_mfma_f32_16x16x32_f16(A[kt], b[1][kt], acc1, 0, 0, 0);
        }

        _Float16* Og = Ob + g * (16 * TSTRIDE);
#pragma unroll
        for (int i = 0; i < 4; i++) {
            Og[(quad * 4 + i) * TSTRIDE + s * 32 + col16] = (_Float16)(acc0[i] + bias0);
            Og[(quad * 4 + i) * TSTRIDE + s * 32 + 16 + col16] = (_Float16)(acc1[i] + bias1);
        }

        asm volatile("s_waitcnt vmcnt(1) lgkmcnt(0)" ::: "memory");
        __builtin_amdgcn_s_barrier();
        __builtin_amdgcn_sched_barrier(0);

        f16x8 v = *(const f16x8*)&Ob[ek * (16 * TSTRIDE) + erow * TSTRIDE + ec8 * 8];
        *(f16x8*)(t_out + ((size_t)ek * N + (r0 + erow)) * DF + ec8 * 8) = v;
    }
    asm volatile("s_waitcnt vmcnt(0)" ::: "memory");
}

// a[n][:] = sum over incoming edges of t[et][src][:] (R0-R5 verified; near the
// random-gather roofline: 153.6MB of 256B rows at ~4TB/s effective)
__global__ __launch_bounds__(256) void k_agg(
    const _Float16* __restrict__ t, const int* __restrict__ row_start,
    const int* __restrict__ csr, _Float16* __restrict__ ah, int N) {
    const int wave = threadIdx.x >> 6, lane = threadIdx.x & 63;
    const int g4 = lane >> 4;
    const int c8 = lane & 15;
    const int n = blockIdx.x * 4 + wave;
    const int beg = row_start[n], end = row_start[n + 1];
    float acc[8] = {0.f, 0.f, 0.f, 0.f, 0.f, 0.f, 0.f, 0.f};
    for (int e = beg; e < end; e += 16) {
        int i0 = e + g4, i1 = e + 4 + g4, i2 = e + 8 + g4, i3 = e + 12 + g4;
        float m0 = (i0 < end) ? 1.0f : 0.0f;
        float m1 = (i1 < end) ? 1.0f : 0.0f;
        float m2 = (i2 < end) ? 1.0f : 0.0f;
        float m3 = (i3 < end) ? 1.0f : 0.0f;
        int j0 = (i0 < end) ? i0 : end - 1;
        int j1 = (i1 < end) ? i1 : end - 1;
        int j2 = (i2 < end) ? i2 : end - 1;
        int j3 = (i3 < end) ? i3 : end - 1;
        int p0 = csr[j0], p1 = csr[j1], p2 = csr[j2], p3 = csr[j3];
        f16x8 x0 = *(const f16x8*)(t + ((((size_t)(p0 >> 16)) * N + (p0 & 0xFFFF)) << 7) + c8 * 8);
        f16x8 x1 = *(const f16x8*)(t + ((((size_t)(p1 >> 16)) * N + (p1 & 0xFFFF)) << 7) + c8 * 8);
        f16x8 x2 = *(const f16x8*)(t + ((((size_t)(p2 >> 16)) * N + (p2 & 0xFFFF)) << 7) + c8 * 8);
        f16x8 x3 = *(const f16x8*)(t + ((((size_t)(p3 >> 16)) * N + (p3 & 0xFFFF)) << 7) + c8 * 8);
#pragma unroll
        for (int j = 0; j < 8; j++) acc[j] += m0 * (float)x0[j];
#pragma unroll
        for (int j = 0; j < 8; j++) acc[j] += m1 * (float)x1[j];
#pragma unroll
        for (int j = 0; j < 8; j++) acc[j] += m2 * (float)x2[j];
#pragma unroll
        for (int j = 0; j < 8; j++) acc[j] += m3 * (float)x3[j];
    }
#pragma unroll
    for (int j = 0; j < 8; j++) {
        acc[j] += __shfl_xor(acc[j], 32, 64);
        acc[j] += __shfl_xor(acc[j], 16, 64);
    }
    if (lane < 16) {
        f16x8 o;
#pragma unroll
        for (int j = 0; j < 8; j++) o[j] = (_Float16)acc[j];
        *(f16x8*)(ah + ((size_t)n << 7) + c8 * 8) = o;
    }
}

// GRU, gate-in-wave: 8 waves x 16 output cols; each wave computes ALL THREE
// gates for its cols (br/bz K=256, bi/bh K=128 halves; 24 persistent frags,
// 24 MFMA/tile). r,z,n,hn land in the SAME lane at the same (row,col) -> the
// GRU elementwise fuses IN REGISTERS. Deletes R3's X exchange (66KB LDS,
// 16 ds_write + 12 ds_read per thread, 800K bank conflicts). Keeps the Ast
// ring + one counted-vmcnt barrier per tile. h_next stored via wave-private
// LDS transpose (same-wave RAW, no barrier). Final step: f16 h_next is dead,
// write only out_f32 (coalesced 64B/row).
__global__ __launch_bounds__(512) void k_gru(
    const _Float16* __restrict__ ah, const _Float16* __restrict__ hh,
    const _Float16* __restrict__ Bc, const float* __restrict__ b_ih,
    const float* __restrict__ b_hh, _Float16* __restrict__ hh_next,
    float* __restrict__ out_f32) {
    __shared__ __align__(16) char Ast[4][8192];      // A-tile ring: [slot][ah 4KB | hh 4KB]
    __shared__ _Float16 Tw[8][16][20];               // per-wave transpose (stride 20: 8B-aligned rows)
    const int wave = threadIdx.x >> 6, lane = threadIdx.x & 63;
    const int col16 = lane & 15, quad = lane >> 4;
    const int c = wave * 16 + col16;                 // output col 0..127

    // persistent B frags: Bc[gate*128 + c][k], k = kt*32 + quad*8
    f16x8 br[8], bz[8], bi[4], bh[4];
    {
        const _Float16* Br = Bc + ((size_t)c << 8);
        const _Float16* Bz = Bc + ((size_t)(128 + c) << 8);
        const _Float16* Bn = Bc + ((size_t)(256 + c) << 8);
#pragma unroll
        for (int kt = 0; kt < 8; kt++) {
            br[kt] = *(const f16x8*)(Br + kt * 32 + quad * 8);
            bz[kt] = *(const f16x8*)(Bz + kt * 32 + quad * 8);
        }
#pragma unroll
        for (int kt = 0; kt < 4; kt++) {
            bi[kt] = *(const f16x8*)(Bn + kt * 32 + quad * 8);          // k<128: a part
            bh[kt] = *(const f16x8*)(Bn + 128 + kt * 32 + quad * 8);    // k>=128: h part
        }
    }
    // col-fixed biases hoisted
    const float bir = b_ih[c] + b_hh[c];
    const float biz = b_ih[128 + c] + b_hh[128 + c];
    const float bin_ = b_ih[256 + c];
    const float bhn_ = b_hh[256 + c];

    const int olocal = (wave & 3) * 1024 + lane * 16;
    const int oswl = olocal ^ (((olocal >> 8) & 7) << 4);
    const char* sbase = (wave < 4) ? (const char*)ah : (const char*)hh;
    const int abase = col16 * 256 + quad * 16;
    const int axor = (col16 & 7) << 4;

    auto STAGE = [&](int iter) {
        int tt = blockIdx.x + iter * GRU_BLOCKS;
        if (tt >= GRU_TILES) tt = GRU_TILES - 1;     // clamp keeps vmcnt accounting uniform
        const char* gp = sbase + (size_t)tt * 4096 + oswl;
        char* lp = &Ast[iter & 3][wave * 1024];      // wave-uniform base; HW adds lane*16
        __builtin_amdgcn_global_load_lds(
            (const __attribute__((address_space(1))) void*)gp,
            (__attribute__((address_space(3))) void*)lp, 16, 0, 0);
    };

    STAGE(0);
    STAGE(1);
    asm volatile("s_waitcnt vmcnt(1)" ::: "memory");
    __builtin_amdgcn_s_barrier();
    __builtin_amdgcn_sched_barrier(0);

    int it = 0;
    for (int tile = blockIdx.x; tile < GRU_TILES; tile += GRU_BLOCKS, ++it) {
        const int r0 = tile * 16;
        STAGE(it + 2);                               // 2-deep prefetch into ring slot

        const char* As = (const char*)Ast[it & 3];

        f16x8 A[8];                                  // kt<4 = ah part, kt>=4 = hh part
#pragma unroll
        for (int kt = 0; kt < 8; kt++) {
            int off = ((kt & 4) << 10) + abase + (kt & 3) * 64;
            off ^= axor;
            A[kt] = *(const f16x8*)(As + off);
        }

        f32x4 ar = {0.f, 0.f, 0.f, 0.f}, az = {0.f, 0.f, 0.f, 0.f};
        f32x4 ai = {0.f, 0.f, 0.f, 0.f}, an = {0.f, 0.f, 0.f, 0.f};
#pragma unroll
        for (int kt = 0; kt < 8; kt++) {
            ar = __builtin_amdgcn_mfma_f32_16x16x32_f16(A[kt], br[kt], ar, 0, 0, 0);
            az = __builtin_amdgcn_mfma_f32_16x16x32_f16(A[kt], bz[kt], az, 0, 0, 0);
        }
#pragma unroll
        for (int kt = 0; kt < 4; kt++) {
            ai = __builtin_amdgcn_mfma_f32_16x16x32_f16(A[kt], bi[kt], ai, 0, 0, 0);
            an = __builtin_amdgcn_mfma_f32_16x16x32_f16(A[4 + kt], bh[kt], an, 0, 0, 0);
        }

        // in-register GRU epilogue: all four gate values co-located per lane
#pragma unroll
        for (int i = 0; i < 4; i++) {
            int row = quad * 4 + i;
            int hoff = (4096 + row * 256 + c * 2) ^ ((row & 7) << 4);
            float hprev = (float)*(const _Float16*)(As + hoff);
            float r = sigmoid_fast(ar[i] + bir);
            float z = sigmoid_fast(az[i] + biz);
            float nn = tanh_fast(ai[i] + bin_ + r * (an[i] + bhn_));
            float hv = (1.f - z) * nn + z * hprev;
            if (out_f32) {
                out_f32[((size_t)(r0 + row) << 7) + c] = hv;   // 64B/row coalesced
            } else {
                Tw[wave][row][col16] = (_Float16)hv;
            }
        }
        if (!out_f32) {
            // wave-private readback (same-wave RAW; compiler orders via lgkmcnt)
            int row = lane >> 2, ch = lane & 3;
            f16x4 v = *(const f16x4*)&Tw[wave][row][ch * 4];
            *(f16x4*)(hh_next + ((size_t)(r0 + row) << 7) + wave * 16 + ch * 4) = v;
        }

        asm volatile("s_waitcnt vmcnt(1) lgkmcnt(0)" ::: "memory");
        __builtin_amdgcn_s_barrier();
        __builtin_amdgcn_sched_barrier(0);
    }
    asm volatile("s_waitcnt vmcnt(0)" ::: "memory");
}

// ---------------- launch ----------------

extern "C" void kernel_launch(void* const* d_in, const int* in_sizes, int n_in,
                              void* d_out, int out_size, void* d_ws, size_t ws_size,
                              hipStream_t stream) {
    const float* h0    = (const float*)d_in[0];
    const int*   src   = (const int*)d_in[1];
    const int*   dst   = (const int*)d_in[2];
    const int*   ety   = (const int*)d_in[3];
    const float* W_lin = (const float*)d_in[4];
    const float* b_lin = (const float*)d_in[5];
    const float* w_ih  = (const float*)d_in[6];
    const float* w_hh  = (const float*)d_in[7];
    const float* b_ih  = (const float*)d_in[8];
    const float* b_hh  = (const float*)d_in[9];
    float* hout = (float*)d_out;

    char* p = (char*)d_ws;
    auto alloc = [&](size_t bytes) -> char* {
        char* r = p;
        p += (bytes + 255) & ~(size_t)255;
        return r;
    };
    _Float16* h_a    = (_Float16*)alloc((size_t)N_NODES * DF * 2);
    _Float16* h_b    = (_Float16*)alloc((size_t)N_NODES * DF * 2);
    _Float16* a_half = (_Float16*)alloc((size_t)N_NODES * DF * 2);
    _Float16* t_half = (_Float16*)alloc((size_t)N_ETYPES * N_NODES * DF * 2);
    _Float16* Wl_h   = (_Float16*)alloc((size_t)N_ETYPES * DF * DF * 2);
    _Float16* Bc     = (_Float16*)alloc((size_t)3 * DF * 2 * DF * 2);   // [384][256] f16
    int* deg       = (int*)alloc((size_t)N_NODES * 4);
    int* row_start = (int*)alloc((size_t)(N_NODES + 1) * 4);
    int* cursor    = (int*)alloc((size_t)N_NODES * 4);
    int* csr       = (int*)alloc((size_t)N_EDGES * 4);
    int* part      = (int*)alloc((size_t)SCAN_NB * 4);

    hipMemsetAsync(deg, 0, (size_t)N_NODES * 4, stream);
    k_setup<<<(N_NODES * DF / 4 + 255) / 256, 256, 0, stream>>>(
        W_lin, w_ih, w_hh, h0, dst, Wl_h, Bc, h_a, deg);
    k_part<<<SCAN_NB, 256, 0, stream>>>(deg, part, N_NODES);
    k_scan1<<<1, 256, 0, stream>>>(part, SCAN_NB);
    k_row<<<SCAN_NB, 256, 0, stream>>>(deg, part, row_start, cursor, N_NODES);
    k_fill<<<FILL_CHUNKS * 8, 256, 0, stream>>>(src, dst, ety, cursor, csr, N_EDGES);

    _Float16* hc = h_a;
    _Float16* hn = h_b;
    for (int s = 0; s < N_STEPS; s++) {
        k_lin<<<LIN_BLOCKS, 1024, 0, stream>>>(hc, Wl_h, b_lin, t_half, N_NODES);
        k_agg<<<N_NODES / 4, 256, 0, stream>>>(t_half, row_start, csr, a_half, N_NODES);
        float* of = (s == N_STEPS - 1) ? hout : nullptr;
        k_gru<<<GRU_BLOCKS, 512, 0, stream>>>(a_half, hc, Bc, b_ih, b_hh, hn, of);
        _Float16* tmp = hc; hc = hn; hn = tmp;
    }
}

// Round 8
// 514.142 us; speedup vs baseline: 1.1371x; 1.0159x over previous
//
#include <hip/hip_runtime.h>
#include <hip/hip_bf16.h>
#include <cstdint>
#include <cstddef>

#define N_NODES 50000
#define N_EDGES 600000
#define DF 128
#define N_ETYPES 4
#define N_STEPS 5
#define SCAN_NB 196        // ceil(50000/256)
#define GRU_TILES 3125     // 50000/16 exact
#define GRU_BLOCKS 256     // 1 block/CU
#define LIN_BLOCKS 256     // k_lin (step-0 only): 1024-thread persistent-weight blocks
#define TSTRIDE 136        // k_lin LDS out-tile row stride (f16)
#define OSTR 76            // k_grulin Ow row stride (f16): 38 dwords -> spread banks
#define FILL_CHUNKS 2344   // ceil(600000/256)
#define FILL_RANGE (N_NODES / 8)   // 6250 nodes per XCD range

typedef _Float16 f16x8 __attribute__((ext_vector_type(8)));
typedef _Float16 f16x4 __attribute__((ext_vector_type(4)));
typedef float f32x4 __attribute__((ext_vector_type(4)));

__device__ __forceinline__ float sigmoid_fast(float x) {
    return 1.0f / (1.0f + __expf(-x));
}
__device__ __forceinline__ float tanh_fast(float x) {
    return 1.0f - 2.0f / (__expf(2.0f * x) + 1.0f);
}

// ---------------- setup kernels (once per launch) ----------------

// merged: Wl->f16 + Bc build + h->f16 + degree histogram
__global__ __launch_bounds__(256) void k_setup(
    const float* __restrict__ Wl, const float* __restrict__ wih,
    const float* __restrict__ whh, const float* __restrict__ h,
    const int* __restrict__ dst,
    _Float16* __restrict__ Wl_h, _Float16* __restrict__ Bc,
    _Float16* __restrict__ hh, int* __restrict__ deg) {
    int i = blockIdx.x * 256 + threadIdx.x;
    if (i < N_ETYPES * DF * DF * 3 / 2) {            // 98304: Bc (+ Wl_h for i<65536)
        if (i < N_ETYPES * DF * DF) Wl_h[i] = (_Float16)Wl[i];
        int row = i >> 8;                            // 0..383 = g*128 + c
        int k = i & 255;
        float v = (k < 128) ? wih[row * 128 + k] : whh[row * 128 + (k - 128)];
        Bc[i] = (_Float16)v;
    }
    if (i < N_NODES * DF / 4) {                      // 1.6M float4 chunks
        float4 v = ((const float4*)h)[i];
        f16x4 o;
        o.x = (_Float16)v.x; o.y = (_Float16)v.y;
        o.z = (_Float16)v.z; o.w = (_Float16)v.w;
        ((f16x4*)hh)[i] = o;
    }
    if (i < N_EDGES) atomicAdd(&deg[dst[i]], 1);
}

// hierarchical exclusive scan over deg[0..N)
__global__ __launch_bounds__(256) void k_part(
    const int* __restrict__ deg, int* __restrict__ part, int N) {
    __shared__ int s[256];
    int t = threadIdx.x, i = blockIdx.x * 256 + t;
    s[t] = (i < N) ? deg[i] : 0;
    __syncthreads();
    for (int off = 128; off > 0; off >>= 1) {
        if (t < off) s[t] += s[t + off];
        __syncthreads();
    }
    if (t == 0) part[blockIdx.x] = s[0];
}

__global__ __launch_bounds__(256) void k_scan1(int* __restrict__ part, int nb) {
    __shared__ int s[256];
    int t = threadIdx.x;
    int v = (t < nb) ? part[t] : 0;
    s[t] = v;
    __syncthreads();
    for (int off = 1; off < 256; off <<= 1) {
        int u = (t >= off) ? s[t - off] : 0;
        __syncthreads();
        s[t] += u;
        __syncthreads();
    }
    if (t < nb) part[t] = s[t] - v;
}

__global__ __launch_bounds__(256) void k_row(
    const int* __restrict__ deg, const int* __restrict__ part,
    int* __restrict__ row_start, int* __restrict__ cursor, int N) {
    __shared__ int s[256];
    int t = threadIdx.x, i = blockIdx.x * 256 + t;
    int d = (i < N) ? deg[i] : 0;
    s[t] = d;
    __syncthreads();
    for (int off = 1; off < 256; off <<= 1) {
        int u = (t >= off) ? s[t - off] : 0;
        __syncthreads();
        s[t] += u;
        __syncthreads();
    }
    int rs = part[blockIdx.x] + s[t] - d;
    if (i < N) {
        row_start[i] = rs;
        cursor[i] = rs;
        if (i == N - 1) row_start[N] = rs + d;
    }
}

// XCD-partitioned CSR scatter (R5 verified win: WRITE_SIZE 36.7MB -> ~4MB).
__global__ __launch_bounds__(256) void k_fill(
    const int* __restrict__ src, const int* __restrict__ dst,
    const int* __restrict__ ety, int* __restrict__ cursor,
    int* __restrict__ csr, int E) {
    const int range = blockIdx.x & 7;
    const int chunk = blockIdx.x >> 3;
    const int e = chunk * 256 + threadIdx.x;
    const int lo = range * FILL_RANGE;
    const int hi = lo + FILL_RANGE;
    if (e < E) {
        int d = dst[e];
        if (d >= lo && d < hi) {
            int slot = atomicAdd(&cursor[d], 1);
            csr[slot] = src[e] | ((ety[e] - 1) << 16);   // src < 65536, et in 0..3
        }
    }
}

// ---------------- per-step kernels ----------------

// t[k][n][f] = sum_d h[n,d] * W[k][f,d] + b_lin[k][f]  (R4 verified; now runs
// ONCE for t_0 -- steps 1..4 get t from the fused k_grulin)
__global__ __launch_bounds__(1024) void k_lin(
    const _Float16* __restrict__ hh, const _Float16* __restrict__ Wl,
    const float* __restrict__ b_lin, _Float16* __restrict__ t_out, int N) {
    __shared__ _Float16 O[2][N_ETYPES * 16 * TSTRIDE];
    __shared__ __align__(16) char Ast[4][4096];
    const int wave = threadIdx.x >> 6, lane = threadIdx.x & 63;
    const int col16 = lane & 15, quad = lane >> 4;
    const int g = wave >> 2;
    const int s = wave & 3;

    f16x8 b[2][4];
#pragma unroll
    for (int ct = 0; ct < 2; ct++) {
        const _Float16* bp = Wl + (size_t)g * DF * DF
                           + (size_t)(s * 32 + ct * 16 + col16) * DF + quad * 8;
#pragma unroll
        for (int kt = 0; kt < 4; kt++) b[ct][kt] = *(const f16x8*)(bp + kt * 32);
    }
    const float bias0 = b_lin[g * DF + s * 32 + col16];
    const float bias1 = b_lin[g * DF + s * 32 + 16 + col16];

    const int olocal = (wave & 3) * 1024 + lane * 16;
    const int oswl = olocal ^ (((olocal >> 8) & 7) << 4);
    const int abase = col16 * 256 + quad * 16;
    const int axor = (col16 & 7) << 4;

    auto STAGE = [&](int iter) {
        if (wave < 4) {
            int tt = blockIdx.x + iter * LIN_BLOCKS;
            if (tt >= GRU_TILES) tt = GRU_TILES - 1;
            const char* gp = (const char*)hh + (size_t)tt * 4096 + oswl;
            char* lp = &Ast[iter & 3][(wave & 3) * 1024];
            __builtin_amdgcn_global_load_lds(
                (const __attribute__((address_space(1))) void*)gp,
                (__attribute__((address_space(3))) void*)lp, 16, 0, 0);
        }
    };

    const int ek = threadIdx.x >> 8;
    const int erow = (threadIdx.x & 255) >> 4;
    const int ec8 = threadIdx.x & 15;

    STAGE(0);
    STAGE(1);
    asm volatile("s_waitcnt vmcnt(1)" ::: "memory");
    __builtin_amdgcn_s_barrier();
    __builtin_amdgcn_sched_barrier(0);

    int it = 0;
    for (int tile = blockIdx.x; tile < GRU_TILES; tile += LIN_BLOCKS, ++it) {
        const int r0 = tile * 16;
        STAGE(it + 2);

        const char* As = (const char*)Ast[it & 3];
        _Float16* Ob = O[it & 1];

        f16x8 A[4];
#pragma unroll
        for (int kt = 0; kt < 4; kt++) {
            int off = (abase + kt * 64) ^ axor;
            A[kt] = *(const f16x8*)(As + off);
        }

        f32x4 acc0 = {0.f, 0.f, 0.f, 0.f}, acc1 = {0.f, 0.f, 0.f, 0.f};
#pragma unroll
        for (int kt = 0; kt < 4; kt++) {
            acc0 = __builtin_amdgcn_mfma_f32_16x16x32_f16(A[kt], b[0][kt], acc0, 0, 0, 0);
            acc1 = __builtin_amdgcn_mfma_f32_16x16x32_f16(A[kt], b[1][kt], acc1, 0, 0, 0);
        }

        _Float16* Og = Ob + g * (16 * TSTRIDE);
#pragma unroll
        for (int i = 0; i < 4; i++) {
            Og[(quad * 4 + i) * TSTRIDE + s * 32 + col16] = (_Float16)(acc0[i] + bias0);
            Og[(quad * 4 + i) * TSTRIDE + s * 32 + 16 + col16] = (_Float16)(acc1[i] + bias1);
        }

        asm volatile("s_waitcnt vmcnt(1) lgkmcnt(0)" ::: "memory");
        __builtin_amdgcn_s_barrier();
        __builtin_amdgcn_sched_barrier(0);

        f16x8 v = *(const f16x8*)&Ob[ek * (16 * TSTRIDE) + erow * TSTRIDE + ec8 * 8];
        *(f16x8*)(t_out + ((size_t)ek * N + (r0 + erow)) * DF + ec8 * 8) = v;
    }
    asm volatile("s_waitcnt vmcnt(0)" ::: "memory");
}

// a[n][:] = sum over incoming edges of t[et][src][:] (verified; at the random
// 256B-gather roofline ~4TB/s from L3)
__global__ __launch_bounds__(256) void k_agg(
    const _Float16* __restrict__ t, const int* __restrict__ row_start,
    const int* __restrict__ csr, _Float16* __restrict__ ah, int N) {
    const int wave = threadIdx.x >> 6, lane = threadIdx.x & 63;
    const int g4 = lane >> 4;
    const int c8 = lane & 15;
    const int n = blockIdx.x * 4 + wave;
    const int beg = row_start[n], end = row_start[n + 1];
    float acc[8] = {0.f, 0.f, 0.f, 0.f, 0.f, 0.f, 0.f, 0.f};
    for (int e = beg; e < end; e += 16) {
        int i0 = e + g4, i1 = e + 4 + g4, i2 = e + 8 + g4, i3 = e + 12 + g4;
        float m0 = (i0 < end) ? 1.0f : 0.0f;
        float m1 = (i1 < end) ? 1.0f : 0.0f;
        float m2 = (i2 < end) ? 1.0f : 0.0f;
        float m3 = (i3 < end) ? 1.0f : 0.0f;
        int j0 = (i0 < end) ? i0 : end - 1;
        int j1 = (i1 < end) ? i1 : end - 1;
        int j2 = (i2 < end) ? i2 : end - 1;
        int j3 = (i3 < end) ? i3 : end - 1;
        int p0 = csr[j0], p1 = csr[j1], p2 = csr[j2], p3 = csr[j3];
        f16x8 x0 = *(const f16x8*)(t + ((((size_t)(p0 >> 16)) * N + (p0 & 0xFFFF)) << 7) + c8 * 8);
        f16x8 x1 = *(const f16x8*)(t + ((((size_t)(p1 >> 16)) * N + (p1 & 0xFFFF)) << 7) + c8 * 8);
        f16x8 x2 = *(const f16x8*)(t + ((((size_t)(p2 >> 16)) * N + (p2 & 0xFFFF)) << 7) + c8 * 8);
        f16x8 x3 = *(const f16x8*)(t + ((((size_t)(p3 >> 16)) * N + (p3 & 0xFFFF)) << 7) + c8 * 8);
#pragma unroll
        for (int j = 0; j < 8; j++) acc[j] += m0 * (float)x0[j];
#pragma unroll
        for (int j = 0; j < 8; j++) acc[j] += m1 * (float)x1[j];
#pragma unroll
        for (int j = 0; j < 8; j++) acc[j] += m2 * (float)x2[j];
#pragma unroll
        for (int j = 0; j < 8; j++) acc[j] += m3 * (float)x3[j];
    }
#pragma unroll
    for (int j = 0; j < 8; j++) {
        acc[j] += __shfl_xor(acc[j], 32, 64);
        acc[j] += __shfl_xor(acc[j], 16, 64);
    }
    if (lane < 16) {
        f16x8 o;
#pragma unroll
        for (int j = 0; j < 8; j++) o[j] = (_Float16)acc[j];
        *(f16x8*)(ah + ((size_t)n << 7) + c8 * 8) = o;
    }
}

// FUSED GRU + next-step linear. gru part = R7's verified gate-in-wave (8 waves
// x 16 cols x 3 gates, 24 persistent B frags, in-register elementwise). NEW:
// h_next goes to a XOR-swizzled LDS tile Hn (same layout math as the ring);
// after one barrier each wave runs the NEXT step's W@h_next for its
// (etype = wave>>1, col-half = wave&1) slice: 16 persistent W frags, 16 MFMA.
// Eliminates k_lin for steps 1-4 (launch + full h round-trip + its own
// per-tile barrier structure). Global stores (h_next, t) are issued AFTER the
// bottom counted-vmcnt barrier so their completion rides into the next tile
// instead of being drained by vmcnt(1). Last step (t_out==nullptr): lin part
// and Hn skipped; behaves like R7's k_gru writing out_f32 only.
__global__ __launch_bounds__(512) void k_grulin(
    const _Float16* __restrict__ ah, const _Float16* __restrict__ hh,
    const _Float16* __restrict__ Bc, const float* __restrict__ b_ih,
    const float* __restrict__ b_hh, const _Float16* __restrict__ Wl,
    const float* __restrict__ b_lin, _Float16* __restrict__ hh_next,
    _Float16* __restrict__ t_out, float* __restrict__ out_f32, int N) {
    __shared__ __align__(16) char Ast[4][8192];      // A-tile ring: [slot][ah 4KB | hh 4KB]
    __shared__ __align__(16) char Hn[2][4096];       // h_next tile, XOR-swizzled, dbuf
    __shared__ _Float16 Ow[8][16 * OSTR];            // per-wave t transpose
    const int wave = threadIdx.x >> 6, lane = threadIdx.x & 63;
    const int col16 = lane & 15, quad = lane >> 4;
    const int c = wave * 16 + col16;                 // gru output col 0..127

    // gru persistent B frags (R7 verified)
    f16x8 br[8], bz[8], bi[4], bh[4];
    {
        const _Float16* Br = Bc + ((size_t)c << 8);
        const _Float16* Bz = Bc + ((size_t)(128 + c) << 8);
        const _Float16* Bn = Bc + ((size_t)(256 + c) << 8);
#pragma unroll
        for (int kt = 0; kt < 8; kt++) {
            br[kt] = *(const f16x8*)(Br + kt * 32 + quad * 8);
            bz[kt] = *(const f16x8*)(Bz + kt * 32 + quad * 8);
        }
#pragma unroll
        for (int kt = 0; kt < 4; kt++) {
            bi[kt] = *(const f16x8*)(Bn + kt * 32 + quad * 8);
            bh[kt] = *(const f16x8*)(Bn + 128 + kt * 32 + quad * 8);
        }
    }
    const float bir = b_ih[c] + b_hh[c];
    const float biz = b_ih[128 + c] + b_hh[128 + c];
    const float bin_ = b_ih[256 + c];
    const float bhn_ = b_hh[256 + c];

    // lin persistent W frags: wave -> (etype, 64-col half); cols ch64+ct*16+col16
    const int et = wave >> 1;
    const int ch64 = (wave & 1) * 64;
    f16x8 wl[4][4];
    float blv[4];
#pragma unroll
    for (int ct = 0; ct < 4; ct++) {
        const _Float16* wp = Wl + (size_t)et * DF * DF
                           + (size_t)(ch64 + ct * 16 + col16) * DF + quad * 8;
#pragma unroll
        for (int kt = 0; kt < 4; kt++) wl[ct][kt] = *(const f16x8*)(wp + kt * 32);
        blv[ct] = b_lin[et * DF + ch64 + ct * 16 + col16];
    }

    const int olocal = (wave & 3) * 1024 + lane * 16;
    const int oswl = olocal ^ (((olocal >> 8) & 7) << 4);
    const char* sbase = (wave < 4) ? (const char*)ah : (const char*)hh;
    const int abase = col16 * 256 + quad * 16;
    const int axor = (col16 & 7) << 4;

    auto STAGE = [&](int iter) {
        int tt = blockIdx.x + iter * GRU_BLOCKS;
        if (tt >= GRU_TILES) tt = GRU_TILES - 1;     // clamp keeps vmcnt accounting uniform
        const char* gp = sbase + (size_t)tt * 4096 + oswl;
        char* lp = &Ast[iter & 3][wave * 1024];
        __builtin_amdgcn_global_load_lds(
            (const __attribute__((address_space(1))) void*)gp,
            (__attribute__((address_space(3))) void*)lp, 16, 0, 0);
    };

    STAGE(0);
    STAGE(1);
    asm volatile("s_waitcnt vmcnt(1)" ::: "memory");
    __builtin_amdgcn_s_barrier();
    __builtin_amdgcn_sched_barrier(0);

    int it = 0;
    for (int tile = blockIdx.x; tile < GRU_TILES; tile += GRU_BLOCKS, ++it) {
        const int r0 = tile * 16;
        STAGE(it + 2);

        const char* As = (const char*)Ast[it & 3];

        f16x8 A[8];                                  // kt<4 = ah part, kt>=4 = hh part
#pragma unroll
        for (int kt = 0; kt < 8; kt++) {
            int off = ((kt & 4) << 10) + abase + (kt & 3) * 64;
            off ^= axor;
            A[kt] = *(const f16x8*)(As + off);
        }

        f32x4 ar = {0.f, 0.f, 0.f, 0.f}, az = {0.f, 0.f, 0.f, 0.f};
        f32x4 ai = {0.f, 0.f, 0.f, 0.f}, an = {0.f, 0.f, 0.f, 0.f};
#pragma unroll
        for (int kt = 0; kt < 8; kt++) {
            ar = __builtin_amdgcn_mfma_f32_16x16x32_f16(A[kt], br[kt], ar, 0, 0, 0);
            az = __builtin_amdgcn_mfma_f32_16x16x32_f16(A[kt], bz[kt], az, 0, 0, 0);
        }
#pragma unroll
        for (int kt = 0; kt < 4; kt++) {
            ai = __builtin_amdgcn_mfma_f32_16x16x32_f16(A[kt], bi[kt], ai, 0, 0, 0);
            an = __builtin_amdgcn_mfma_f32_16x16x32_f16(A[4 + kt], bh[kt], an, 0, 0, 0);
        }

        // in-register GRU epilogue
        char* Hb = Hn[it & 1];
#pragma unroll
        for (int i = 0; i < 4; i++) {
            int row = quad * 4 + i;
            int hoff = (4096 + row * 256 + c * 2) ^ ((row & 7) << 4);
            float hprev = (float)*(const _Float16*)(As + hoff);
            float r = sigmoid_fast(ar[i] + bir);
            float z = sigmoid_fast(az[i] + biz);
            float nn = tanh_fast(ai[i] + bin_ + r * (an[i] + bhn_));
            float hv = (1.f - z) * nn + z * hprev;
            if (out_f32) {
                out_f32[((size_t)(r0 + row) << 7) + c] = hv;   // last step: direct
            } else {
                // h_next -> swizzled LDS tile (ring layout math, verified)
                *(_Float16*)(Hb + ((row * 256 + c * 2) ^ ((row & 7) << 4))) = (_Float16)hv;
            }
        }

        if (t_out) {
            // barrier #1: Hn complete across waves, then next-step lin
            asm volatile("s_waitcnt lgkmcnt(0)" ::: "memory");
            __builtin_amdgcn_s_barrier();
            __builtin_amdgcn_sched_barrier(0);

            f16x8 A2[4];
#pragma unroll
            for (int kt = 0; kt < 4; kt++) {
                int off = (col16 * 256 + kt * 64 + quad * 16) ^ ((col16 & 7) << 4);
                A2[kt] = *(const f16x8*)(Hb + off);
            }
#pragma unroll
            for (int ct = 0; ct < 4; ct++) {
                f32x4 acc = {0.f, 0.f, 0.f, 0.f};
#pragma unroll
                for (int kt = 0; kt < 4; kt++)
                    acc = __builtin_amdgcn_mfma_f32_16x16x32_f16(A2[kt], wl[ct][kt], acc, 0, 0, 0);
#pragma unroll
                for (int i = 0; i < 4; i++)
                    Ow[wave][(quad * 4 + i) * OSTR + ct * 16 + col16] = (_Float16)(acc[i] + blv[ct]);
            }
        }

        // bottom barrier: ring slot it+1 landed; LDS visible. Prefetch stays in
        // flight (vmcnt(1), never 0 in-loop).
        asm volatile("s_waitcnt vmcnt(1) lgkmcnt(0)" ::: "memory");
        __builtin_amdgcn_s_barrier();
        __builtin_amdgcn_sched_barrier(0);

        // post-barrier global stores: completion rides into the next tile
        // (the next bottom vmcnt(1) sees them a full tile later -> free).
        if (!out_f32) {
            int hrow = threadIdx.x >> 5, hch = threadIdx.x & 31;
            f16x4 hv4 = *(const f16x4*)(Hb + ((hrow * 256 + hch * 8) ^ ((hrow & 7) << 4)));
            *(f16x4*)(hh_next + ((size_t)(r0 + hrow) << 7) + hch * 4) = hv4;
        }
        if (t_out) {
#pragma unroll
            for (int j = 0; j < 2; j++) {
                int chunk = lane + 64 * j;           // 0..127
                int trow = chunk >> 3, c8 = chunk & 7;
                f16x8 v = *(const f16x8*)&Ow[wave][trow * OSTR + c8 * 8];
                *(f16x8*)(t_out + ((size_t)et * N + (r0 + trow)) * DF + ch64 + c8 * 8) = v;
            }
        }
    }
    asm volatile("s_waitcnt vmcnt(0)" ::: "memory");
}

// ---------------- launch ----------------

extern "C" void kernel_launch(void* const* d_in, const int* in_sizes, int n_in,
                              void* d_out, int out_size, void* d_ws, size_t ws_size,
                              hipStream_t stream) {
    const float* h0    = (const float*)d_in[0];
    const int*   src   = (const int*)d_in[1];
    const int*   dst   = (const int*)d_in[2];
    const int*   ety   = (const int*)d_in[3];
    const float* W_lin = (const float*)d_in[4];
    const float* b_lin = (const float*)d_in[5];
    const float* w_ih  = (const float*)d_in[6];
    const float* w_hh  = (const float*)d_in[7];
    const float* b_ih  = (const float*)d_in[8];
    const float* b_hh  = (const float*)d_in[9];
    float* hout = (float*)d_out;

    char* p = (char*)d_ws;
    auto alloc = [&](size_t bytes) -> char* {
        char* r = p;
        p += (bytes + 255) & ~(size_t)255;
        return r;
    };
    _Float16* h_a    = (_Float16*)alloc((size_t)N_NODES * DF * 2);
    _Float16* h_b    = (_Float16*)alloc((size_t)N_NODES * DF * 2);
    _Float16* a_half = (_Float16*)alloc((size_t)N_NODES * DF * 2);
    _Float16* t_half = (_Float16*)alloc((size_t)N_ETYPES * N_NODES * DF * 2);
    _Float16* Wl_h   = (_Float16*)alloc((size_t)N_ETYPES * DF * DF * 2);
    _Float16* Bc     = (_Float16*)alloc((size_t)3 * DF * 2 * DF * 2);   // [384][256] f16
    int* deg       = (int*)alloc((size_t)N_NODES * 4);
    int* row_start = (int*)alloc((size_t)(N_NODES + 1) * 4);
    int* cursor    = (int*)alloc((size_t)N_NODES * 4);
    int* csr       = (int*)alloc((size_t)N_EDGES * 4);
    int* part      = (int*)alloc((size_t)SCAN_NB * 4);

    hipMemsetAsync(deg, 0, (size_t)N_NODES * 4, stream);
    k_setup<<<(N_NODES * DF / 4 + 255) / 256, 256, 0, stream>>>(
        W_lin, w_ih, w_hh, h0, dst, Wl_h, Bc, h_a, deg);
    k_part<<<SCAN_NB, 256, 0, stream>>>(deg, part, N_NODES);
    k_scan1<<<1, 256, 0, stream>>>(part, SCAN_NB);
    k_row<<<SCAN_NB, 256, 0, stream>>>(deg, part, row_start, cursor, N_NODES);
    k_fill<<<FILL_CHUNKS * 8, 256, 0, stream>>>(src, dst, ety, cursor, csr, N_EDGES);

    _Float16* hc = h_a;
    _Float16* hn = h_b;
    k_lin<<<LIN_BLOCKS, 1024, 0, stream>>>(hc, Wl_h, b_lin, t_half, N_NODES);
    for (int s = 0; s < N_STEPS; s++) {
        k_agg<<<N_NODES / 4, 256, 0, stream>>>(t_half, row_start, csr, a_half, N_NODES);
        const bool last = (s == N_STEPS - 1);
        k_grulin<<<GRU_BLOCKS, 512, 0, stream>>>(
            a_half, hc, Bc, b_ih, b_hh, Wl_h, b_lin, hn,
            last ? nullptr : t_half, last ? hout : nullptr, N_NODES);
        _Float16* tmp = hc; hc = hn; hn = tmp;
    }
}